// Round 8
// baseline (1763.837 us; speedup 1.0000x reference)
//
#include <hip/hip_runtime.h>

#define HH 64
#define WW 64
#define TT 100
#define CO 8
#define COB 4                      // couts per block
#define KS 6
#define LP 2
#define HALO 21                    // 16 + 6 - 1
#define NSITE 441                  // 21*21
#define NG 5                       // 20 timesteps per chunk (5 float4-groups)

__device__ __forceinline__ float stepu(float u, float s, float th, float wx) {
    // u = (u - s*th) + wx  -- exact reference association, no contraction
    return __fadd_rn(__fsub_rn(u, __fmul_rn(s, th)), wx);
}

// Stage x[T0..T0+20) halo into LDS, conv (kh-major sequential FMA, bit-exact
// vs np ref), scan; accumulate spike bits in registers (static indices only).
template<int T0>
__device__ __forceinline__ void process_chunk(
    const float* __restrict__ xb,
    float4* __restrict__ xs, const float (*wds)[COB],
    int tid, int r, int c, int h0, int w0, float th,
    float* ut, float* sprev, unsigned* bw /* COB*4 words, static idx */)
{
    for (int i = tid; i < NSITE * NG; i += 256) {
        const int s  = i / NG;
        const int tg = i - s * NG;
        const int hr = s / HALO;
        const int hc = s - hr * HALO;
        const int hh = h0 - LP + hr;
        const int ww = w0 - LP + hc;
        float4 v = make_float4(0.f, 0.f, 0.f, 0.f);
        if ((unsigned)hh < (unsigned)HH && (unsigned)ww < (unsigned)WW)
            v = *(const float4*)(xb + ((size_t)hh * WW + ww) * TT + T0 + tg * 4);
        xs[tg * NSITE + s] = v;
    }
    __syncthreads();

    unsigned cb[COB];
#pragma unroll
    for (int j = 0; j < COB; ++j) cb[j] = 0u;

    for (int tg = 0; tg < NG; ++tg) {
        float4 wx[COB];
#pragma unroll
        for (int j = 0; j < COB; ++j) wx[j] = make_float4(0.f, 0.f, 0.f, 0.f);
#pragma unroll
        for (int kh = 0; kh < KS; ++kh) {
#pragma unroll
            for (int kw = 0; kw < KS; ++kw) {
                const float4 xv = xs[tg * NSITE + (r + kh) * HALO + (c + kw)];
                const int tap = kh * KS + kw;
#pragma unroll
                for (int j = 0; j < COB; ++j) {
                    const float wd = wds[tap][j];
                    wx[j].x = __fmaf_rn(wd, xv.x, wx[j].x);
                    wx[j].y = __fmaf_rn(wd, xv.y, wx[j].y);
                    wx[j].z = __fmaf_rn(wd, xv.z, wx[j].z);
                    wx[j].w = __fmaf_rn(wd, xv.w, wx[j].w);
                }
            }
        }
        const int sh = tg * 4;
#pragma unroll
        for (int j = 0; j < COB; ++j) {
            float u = ut[j], s = sprev[j];
            unsigned m = 0u;
            u = stepu(u, s, th, wx[j].x); s = (u > 0.f) ? 1.f : 0.f; m |= (u > 0.f) ? 1u : 0u;
            u = stepu(u, s, th, wx[j].y); s = (u > 0.f) ? 1.f : 0.f; m |= (u > 0.f) ? 2u : 0u;
            u = stepu(u, s, th, wx[j].z); s = (u > 0.f) ? 1.f : 0.f; m |= (u > 0.f) ? 4u : 0u;
            u = stepu(u, s, th, wx[j].w); s = (u > 0.f) ? 1.f : 0.f; m |= (u > 0.f) ? 8u : 0u;
            ut[j] = u; sprev[j] = s;
            cb[j] |= m << sh;
        }
    }
    __syncthreads();   // compute done before next chunk overwrites xs

    // merge 20 chunk bits into full-T words; word idx & shift compile-time
    constexpr int W0 = T0 / 32;
    constexpr int S  = T0 % 32;
#pragma unroll
    for (int j = 0; j < COB; ++j) {
        bw[j * 4 + W0] |= cb[j] << S;
        if constexpr (S + 20 > 32)
            bw[j * 4 + W0 + 1] |= cb[j] >> ((32 - S) & 31);
    }
}

__global__ __launch_bounds__(256, 4)
void sconv2d_spike_kernel(const float* __restrict__ x,
                          const float* __restrict__ wgt,
                          const float* __restrict__ thresh,
                          float* __restrict__ out)
{
    __shared__ float4   xs[NG * NSITE];       // 35.28 KB
    __shared__ float    wds[KS * KS][COB];    // 576 B (this block's 4 couts)
    __shared__ unsigned stg[256][4];          // 4 KB (reads are broadcasts)
    // total 39.95 KB -> 4 blocks/CU

    const int tid = threadIdx.x;

    // grid = 32 images x 16 tiles x 2 co-halves
    const int blk  = blockIdx.x;
    const int b    = blk >> 5;
    const int rest = blk & 31;
    const int tb   = rest >> 1;
    const int co0  = (rest & 1) * COB;
    const int h0   = (tb >> 2) << 4;
    const int w0   = (tb & 3) << 4;
    const int r    = tid >> 4;
    const int c    = tid & 15;

    for (int i = tid; i < KS * KS * COB; i += 256) {
        const int j   = i / (KS * KS);
        const int tap = i - j * (KS * KS);
        wds[tap][j] = wgt[(co0 + j) * (KS * KS) + tap];
    }
    const float th = thresh[0];

    const float* xb   = x   + (size_t)b * (HH * WW * TT);
    float*       outb = out + (size_t)b * (CO * HH * WW * TT);

    float ut[COB], sprev[COB];
    unsigned bw[COB * 4];
#pragma unroll
    for (int j = 0; j < COB; ++j) { ut[j] = 0.f; sprev[j] = 0.f; }
#pragma unroll
    for (int i = 0; i < COB * 4; ++i) bw[i] = 0u;

    process_chunk< 0>(xb, xs, wds, tid, r, c, h0, w0, th, ut, sprev, bw);
    process_chunk<20>(xb, xs, wds, tid, r, c, h0, w0, th, ut, sprev, bw);
    process_chunk<40>(xb, xs, wds, tid, r, c, h0, w0, th, ut, sprev, bw);
    process_chunk<60>(xb, xs, wds, tid, r, c, h0, w0, th, ut, sprev, bw);
    process_chunk<80>(xb, xs, wds, tid, r, c, h0, w0, th, ut, sprev, bw);

    // ---- flush: per-co bit expansion, full-line coalesced float4 stores ----
#pragma unroll
    for (int j = 0; j < COB; ++j) {
        const int co = co0 + j;
        stg[tid][0] = bw[j * 4 + 0];
        stg[tid][1] = bw[j * 4 + 1];
        stg[tid][2] = bw[j * 4 + 2];
        stg[tid][3] = bw[j * 4 + 3];
        __syncthreads();
#pragma unroll
        for (int k = 0; k < 25; ++k) {
            const int idx = tid + k * 256;        // 0..6399
            const int u   = idx / 25;             // site 0..255
            const int tt  = (idx - u * 25) * 4;   // t0 of this float4 (4-aligned)
            const unsigned bs = stg[u][tt >> 5] >> (tt & 31);
            float4 v;
            v.x = (float)( bs        & 1u);
            v.y = (float)((bs >> 1)  & 1u);
            v.z = (float)((bs >> 2)  & 1u);
            v.w = (float)((bs >> 3)  & 1u);
            const int rr = u >> 4, cc = u & 15;
            *(float4*)(outb + (((size_t)co * HH + (h0 + rr)) * WW + (w0 + cc)) * TT + tt) = v;
        }
        __syncthreads();
    }
}

extern "C" void kernel_launch(void* const* d_in, const int* in_sizes, int n_in,
                              void* d_out, int out_size, void* d_ws, size_t ws_size,
                              hipStream_t stream) {
    const float* x      = (const float*)d_in[0];
    const float* wgt    = (const float*)d_in[1];
    const float* thresh = (const float*)d_in[2];
    float* out = (float*)d_out;

    dim3 grid(32 * 16 * 2);   // images x tiles x co-halves = 1024 (4 per CU)
    dim3 block(256);
    sconv2d_spike_kernel<<<grid, block, 0, stream>>>(x, wgt, thresh, out);
}

// Round 9
// 561.519 us; speedup vs baseline: 3.1412x; 3.1412x over previous
//
#include <hip/hip_runtime.h>

#define HH 64
#define WW 64
#define TT 100
#define CO 8
#define COB 4                      // couts per block
#define KS 6
#define LP 2
#define HALO 21                    // 16 + 6 - 1
#define NSITE 441                  // 21*21
#define NG 5                       // 20 timesteps per chunk (5 float4-groups)

__device__ __forceinline__ float stepu(float u, float s, float th, float wx) {
    // u = (u - s*th) + wx  -- exact reference association, no contraction
    return __fadd_rn(__fsub_rn(u, __fmul_rn(s, th)), wx);
}

// Stage x[T0..T0+20) halo into LDS, conv (kh-major sequential FMA, bit-exact
// vs np ref), scan; accumulate spike bits in registers (static indices only).
template<int T0>
__device__ __forceinline__ void process_chunk(
    const float* __restrict__ xb,
    float4* __restrict__ xs, const float (*wds)[COB],
    int tid, int r, int c, int h0, int w0, float th,
    float* ut, float* sprev, unsigned* bw /* COB*4 words, static idx */)
{
    for (int i = tid; i < NSITE * NG; i += 256) {
        const int s  = i / NG;
        const int tg = i - s * NG;
        const int hr = s / HALO;
        const int hc = s - hr * HALO;
        const int hh = h0 - LP + hr;
        const int ww = w0 - LP + hc;
        float4 v = make_float4(0.f, 0.f, 0.f, 0.f);
        if ((unsigned)hh < (unsigned)HH && (unsigned)ww < (unsigned)WW)
            v = *(const float4*)(xb + ((size_t)hh * WW + ww) * TT + T0 + tg * 4);
        xs[tg * NSITE + s] = v;
    }
    __syncthreads();

    unsigned cb[COB];
#pragma unroll
    for (int j = 0; j < COB; ++j) cb[j] = 0u;

    for (int tg = 0; tg < NG; ++tg) {
        float4 wx[COB];
#pragma unroll
        for (int j = 0; j < COB; ++j) wx[j] = make_float4(0.f, 0.f, 0.f, 0.f);
#pragma unroll
        for (int kh = 0; kh < KS; ++kh) {
#pragma unroll
            for (int kw = 0; kw < KS; ++kw) {
                const float4 xv = xs[tg * NSITE + (r + kh) * HALO + (c + kw)];
                const int tap = kh * KS + kw;
#pragma unroll
                for (int j = 0; j < COB; ++j) {
                    const float wd = wds[tap][j];
                    wx[j].x = __fmaf_rn(wd, xv.x, wx[j].x);
                    wx[j].y = __fmaf_rn(wd, xv.y, wx[j].y);
                    wx[j].z = __fmaf_rn(wd, xv.z, wx[j].z);
                    wx[j].w = __fmaf_rn(wd, xv.w, wx[j].w);
                }
            }
        }
        const int sh = tg * 4;
#pragma unroll
        for (int j = 0; j < COB; ++j) {
            float u = ut[j], s = sprev[j];
            unsigned m = 0u;
            u = stepu(u, s, th, wx[j].x); s = (u > 0.f) ? 1.f : 0.f; m |= (u > 0.f) ? 1u : 0u;
            u = stepu(u, s, th, wx[j].y); s = (u > 0.f) ? 1.f : 0.f; m |= (u > 0.f) ? 2u : 0u;
            u = stepu(u, s, th, wx[j].z); s = (u > 0.f) ? 1.f : 0.f; m |= (u > 0.f) ? 4u : 0u;
            u = stepu(u, s, th, wx[j].w); s = (u > 0.f) ? 1.f : 0.f; m |= (u > 0.f) ? 8u : 0u;
            ut[j] = u; sprev[j] = s;
            cb[j] |= m << sh;
        }
    }
    __syncthreads();   // compute done before next chunk overwrites xs

    // merge 20 chunk bits into full-T words; word idx & shift compile-time
    constexpr int W0 = T0 / 32;
    constexpr int S  = T0 % 32;
#pragma unroll
    for (int j = 0; j < COB; ++j) {
        bw[j * 4 + W0] |= cb[j] << S;
        if constexpr (S + 20 > 32)
            bw[j * 4 + W0 + 1] |= cb[j] >> ((32 - S) & 31);
    }
}

__global__ __launch_bounds__(256, 2)   // (256,4) starved VGPRs to 64 -> 5.6 GB spill (R8)
void sconv2d_spike_kernel(const float* __restrict__ x,
                          const float* __restrict__ wgt,
                          const float* __restrict__ thresh,
                          float* __restrict__ out)
{
    __shared__ float4   xs[NG * NSITE];       // 35.28 KB
    __shared__ float    wds[KS * KS][COB];    // 576 B (this block's 4 couts)
    __shared__ unsigned stg[4][256];          // 4 KB; writes bank=tid%32, conflict-free
    // total 39.95 KB -> 4 blocks/CU (LDS-bound)

    const int tid = threadIdx.x;

    // grid = 32 images x 16 tiles x 2 co-halves
    const int blk  = blockIdx.x;
    const int b    = blk >> 5;
    const int rest = blk & 31;
    const int tb   = rest >> 1;
    const int co0  = (rest & 1) * COB;
    const int h0   = (tb >> 2) << 4;
    const int w0   = (tb & 3) << 4;
    const int r    = tid >> 4;
    const int c    = tid & 15;

    for (int i = tid; i < KS * KS * COB; i += 256) {
        const int j   = i / (KS * KS);
        const int tap = i - j * (KS * KS);
        wds[tap][j] = wgt[(co0 + j) * (KS * KS) + tap];
    }
    const float th = thresh[0];

    const float* xb   = x   + (size_t)b * (HH * WW * TT);
    float*       outb = out + (size_t)b * (CO * HH * WW * TT);

    float ut[COB], sprev[COB];
    unsigned bw[COB * 4];
#pragma unroll
    for (int j = 0; j < COB; ++j) { ut[j] = 0.f; sprev[j] = 0.f; }
#pragma unroll
    for (int i = 0; i < COB * 4; ++i) bw[i] = 0u;

    process_chunk< 0>(xb, xs, wds, tid, r, c, h0, w0, th, ut, sprev, bw);
    process_chunk<20>(xb, xs, wds, tid, r, c, h0, w0, th, ut, sprev, bw);
    process_chunk<40>(xb, xs, wds, tid, r, c, h0, w0, th, ut, sprev, bw);
    process_chunk<60>(xb, xs, wds, tid, r, c, h0, w0, th, ut, sprev, bw);
    process_chunk<80>(xb, xs, wds, tid, r, c, h0, w0, th, ut, sprev, bw);

    // ---- flush: per-co bit expansion, full-line coalesced float4 stores ----
#pragma unroll
    for (int j = 0; j < COB; ++j) {
        const int co = co0 + j;
        stg[0][tid] = bw[j * 4 + 0];
        stg[1][tid] = bw[j * 4 + 1];
        stg[2][tid] = bw[j * 4 + 2];
        stg[3][tid] = bw[j * 4 + 3];
        __syncthreads();
#pragma unroll
        for (int k = 0; k < 25; ++k) {
            const int idx = tid + k * 256;        // 0..6399
            const int u   = idx / 25;             // site 0..255
            const int tt  = (idx - u * 25) * 4;   // t0 of this float4 (4-aligned)
            const unsigned bs = stg[tt >> 5][u] >> (tt & 31);
            float4 v;
            v.x = (float)( bs        & 1u);
            v.y = (float)((bs >> 1)  & 1u);
            v.z = (float)((bs >> 2)  & 1u);
            v.w = (float)((bs >> 3)  & 1u);
            const int rr = u >> 4, cc = u & 15;
            *(float4*)(outb + (((size_t)co * HH + (h0 + rr)) * WW + (w0 + cc)) * TT + tt) = v;
        }
        __syncthreads();
    }
}

extern "C" void kernel_launch(void* const* d_in, const int* in_sizes, int n_in,
                              void* d_out, int out_size, void* d_ws, size_t ws_size,
                              hipStream_t stream) {
    const float* x      = (const float*)d_in[0];
    const float* wgt    = (const float*)d_in[1];
    const float* thresh = (const float*)d_in[2];
    float* out = (float*)d_out;

    dim3 grid(32 * 16 * 2);   // images x tiles x co-halves = 1024 (4 per CU)
    dim3 block(256);
    sconv2d_spike_kernel<<<grid, block, 0, stream>>>(x, wgt, thresh, out);
}